// Round 6
// baseline (125.636 us; speedup 1.0000x reference)
//
#include <hip/hip_runtime.h>
#include <math.h>

#define NW   12
#define DIM  4096
#define TPB  256

typedef float v2f __attribute__((ext_vector_type(2)));   // (re, im) -> v_pk_* f32
typedef unsigned v2u __attribute__((ext_vector_type(2)));

// DPP lane exchange (VALU, no LDS pipe).
// 0xB1=quad XOR1, 0x4E=quad XOR2, 0x1B=quad XOR3, 0x128=row_ror:8 (XOR8), 0x141=row_half_mirror (XOR7).
template<int CTRL>
__device__ __forceinline__ float fdpp(float v) {
    union { float f; int i; } u, w;
    u.f = v;
    w.i = __builtin_amdgcn_update_dpp(0, u.i, CTRL, 0xF, 0xF, false);
    return w.f;
}

// partner at lane^16 / lane^32 via gfx950 permlane*_swap (VALU), LDS fallback.
__device__ __forceinline__ float xor16f(float v, bool hi) {
#if __has_builtin(__builtin_amdgcn_permlane16_swap)
    const v2u pr = __builtin_amdgcn_permlane16_swap(__float_as_uint(v), __float_as_uint(v), false, false);
    return __uint_as_float(hi ? pr.x : pr.y);   // rows1,3 of out0 = rows0,2 of in
#else
    union { float f; int i; } u, w;
    u.f = v;
    w.i = __builtin_amdgcn_ds_swizzle(u.i, 0x401F);   // XOR16 bitmode
    return w.f;
#endif
}
__device__ __forceinline__ float xor32f(float v, bool hi) {
#if __has_builtin(__builtin_amdgcn_permlane32_swap)
    const v2u pr = __builtin_amdgcn_permlane32_swap(__float_as_uint(v), __float_as_uint(v), false, false);
    return __uint_as_float(hi ? pr.x : pr.y);
#else
    return __shfl_xor(v, 32, 64);
#endif
}

// RY on register bit B (0..3 of the 16-amp register file). Packed-f32 VALU.
template<int B>
__device__ __forceinline__ void ry_reg(v2f* r, float c, v2f vps, v2f vms) {
#pragma unroll
    for (int p = 0; p < 8; ++p) {
        const int i0 = ((p >> B) << (B + 1)) | (p & ((1 << B) - 1));
        const int i1 = i0 | (1 << B);
        const v2f a = r[i0], b = r[i1];
        r[i0] = __builtin_elementwise_fma(vms, b, a * c);   // c*a - s*b
        r[i1] = __builtin_elementwise_fma(vps, a, b * c);   // s*a + c*b
    }
}

// RY via single-DPP partner exchange on a lane bit.
template<int CTRL>
__device__ __forceinline__ void ry_dpp(v2f* r, float c, v2f vsp) {
#pragma unroll
    for (int k = 0; k < 16; ++k) {
        const v2f p = { fdpp<CTRL>(r[k].x), fdpp<CTRL>(r[k].y) };
        r[k] = __builtin_elementwise_fma(vsp, p, r[k] * c);
    }
}

// RY on lane bit 2 (XOR4): partner = half_mirror(quad_xor3(x)) -> x[l^7^3] = x[l^4].
__device__ __forceinline__ void ry_xor4(v2f* r, float c, v2f vsp) {
#pragma unroll
    for (int k = 0; k < 16; ++k) {
        const v2f p = { fdpp<0x141>(fdpp<0x1B>(r[k].x)),
                        fdpp<0x141>(fdpp<0x1B>(r[k].y)) };
        r[k] = __builtin_elementwise_fma(vsp, p, r[k] * c);
    }
}

__global__ __launch_bounds__(TPB, 4)
void qmnist_kernel(const float* __restrict__ x,  const float* __restrict__ W1,
                   const float* __restrict__ b1, const float* __restrict__ ryp,
                   const float* __restrict__ rzp, const float* __restrict__ W2,
                   const float* __restrict__ b2, float* __restrict__ out) {
    // Exactly 32 KiB LDS. Small arrays alias the front (state lives in
    // registers whenever they are live; barriers order every transition).
    __shared__ v2f psi[DIM];
    float* smf  = (float*)psi;
    float* wred = smf;        // 48 floats
    float* encc = smf + 48;   // 12
    float* encs = smf + 60;   // 12
    float* zfin = smf + 72;   // 12

    const int tid  = threadIdx.x;
    const int blk  = blockIdx.x;
    const int lane = tid & 63;
    const int wave = tid >> 6;

    // ---------------- phase 0: feat = x[blk] @ W1^T + b1 -> encoding angles
    float acc[NW];
#pragma unroll
    for (int w = 0; w < NW; ++w) acc[w] = 0.f;
    if (tid < 196) {                      // 784 = 196 float4
        const float4 xv = ((const float4*)(x + (size_t)blk * 784))[tid];
#pragma unroll
        for (int w = 0; w < NW; ++w) {
            const float4 wv = ((const float4*)(W1 + w * 784))[tid];
            acc[w] = fmaf(xv.x, wv.x, fmaf(xv.y, wv.y, fmaf(xv.z, wv.z, xv.w * wv.w)));
        }
    }
#pragma unroll
    for (int w = 0; w < NW; ++w) {
        float v = acc[w];
        v += __shfl_down(v, 32);
        v += __shfl_down(v, 16);
        v += __shfl_down(v, 8);
        v += __shfl_down(v, 4);
        v += __shfl_down(v, 2);
        v += __shfl_down(v, 1);
        if (lane == 0) wred[wave * NW + w] = v;
    }
    __syncthreads();
    if (tid < NW) {
        float feat = wred[tid] + wred[NW + tid] + wred[2 * NW + tid] + wred[3 * NW + tid] + b1[tid];
        float a = tanhf(feat) * 3.14159265358979323846f;
        float h = 0.5f * a;
        encc[tid] = cosf(h);
        encs[tid] = sinf(h);
    }
    __syncthreads();

    // ---------------- init product state into REGISTERS.
    // amp index y = (k<<8)|tid; bit b of y <-> wire (11-b). bits 0..7 = tid, 8..11 = k.
    float hi = 1.f;
#pragma unroll
    for (int b = 0; b < 8; ++b)
        hi *= ((tid >> b) & 1) ? encs[11 - b] : encc[11 - b];
    v2f r[16];
#pragma unroll
    for (int k = 0; k < 16; ++k) {
        float f = hi;
        f *= (k & 1) ? encs[3] : encc[3];
        f *= (k & 2) ? encs[2] : encc[2];
        f *= (k & 4) ? encs[1] : encc[1];
        f *= (k & 8) ? encs[0] : encc[0];
        r[k] = (v2f){ f, 0.f };
    }

    // ---------------- variational params.
    // Layer = RY on all 12 positions, RZ on all 12 (folds to popcount phase,
    // layout-invariant), then CNOT staircase new[y] = old[y ^ (y>>1)].
    const float ry = ryp[0], rz = rzp[0];
    const float c = cosf(0.5f * ry), s = sinf(0.5f * ry);
    const v2f vps = {  s,  s };
    const v2f vms = { -s, -s };
    const int pcT = __popc(tid);
    v2f qv[5], qp[5];                    // cis(rz*(pcT+j-6)) and i*cis(...)
#pragma unroll
    for (int j = 0; j < 5; ++j) {
        const float ang = rz * (float)(pcT + j - 6);
        const float qc = cosf(ang), qs = sinf(ang);
        qv[j] = (v2f){  qc, qs };
        qp[j] = (v2f){ -qs, qc };
    }

    // per-lane signed s (splat) for the lane-exchange RY gates (position = lane bit)
    const v2f vs0 = (lane & 1)  ? vps : vms;   // position 0, XOR1  quad_perm
    const v2f vs1 = (lane & 2)  ? vps : vms;   // position 1, XOR2  quad_perm
    const v2f vs2 = (lane & 4)  ? vps : vms;   // position 2, XOR4  chained DPP
    const v2f vs3 = (lane & 8)  ? vps : vms;   // position 3, XOR8  row_ror:8
    const v2f vs4 = (lane & 16) ? vps : vms;   // position 4, XOR16 permlane16_swap
    const v2f vs5 = (lane & 32) ? vps : vms;   // position 5, XOR32 permlane32_swap
    const bool h4 = (lane & 16) != 0;
    const bool h5 = (lane & 32) != 0;

    // RT addressing (identity slot map; every access = ONE base + imm, and
    // slot low4 = t0..t3-rank-4 on all four patterns -> conflict-free b64):
    //  RT-1 write: psi[(k<<8)|tid]                      low4 = t0..3
    //  RT-1 read : rb1 | (k&3)<<6 | (k>>2)<<10          low4 = t0..3
    //  RT-2 write: same slots as RT-1 read (same thread)
    //  RT-2 read : (gt ^ (k&1)<<7) | gray4(k)<<8        low4 = Gray(t0..3), triangular
    const int rb1 = (tid & 63) | ((tid & 192) << 2);     // lane bits + t6,t7 -> slots 8,9
    const int gt  = tid ^ (tid >> 1);                    // Gray of tid (bit7 = t7)

    for (int layer = 0; layer < 3; ++layer) {
        // ---- VALU gates, canonical layout: positions 8-11 (reg bits) ...
        ry_reg<0>(r, c, vps, vms); ry_reg<1>(r, c, vps, vms);
        ry_reg<2>(r, c, vps, vms); ry_reg<3>(r, c, vps, vms);
        // ... and positions 0-5 (lane bits) via DPP / permlane swaps
        ry_dpp<0xB1>(r, c, vs0);
        ry_dpp<0x4E>(r, c, vs1);
        ry_xor4(r, c, vs2);
        ry_dpp<0x128>(r, c, vs3);
#pragma unroll
        for (int k = 0; k < 16; ++k) {
            const v2f p = { xor16f(r[k].x, h4), xor16f(r[k].y, h4) };
            r[k] = __builtin_elementwise_fma(vs4, p, r[k] * c);
        }
#pragma unroll
        for (int k = 0; k < 16; ++k) {
            const v2f p = { xor32f(r[k].x, h5), xor32f(r[k].y, h5) };
            r[k] = __builtin_elementwise_fma(vs5, p, r[k] * c);
        }

        // ---- RT-1: swap positions (6,7) <-> (8,9)
        __syncthreads();                // prior psi readers done
#pragma unroll
        for (int k = 0; k < 16; ++k)
            psi[(k << 8) | tid] = r[k];
        __syncthreads();
#pragma unroll
        for (int k = 0; k < 16; ++k)
            r[k] = psi[rb1 | ((k & 3) << 6) | ((k >> 2) << 10)];

        // gate positions 6,7 (now register bits 0,1)
        ry_reg<0>(r, c, vps, vms); ry_reg<1>(r, c, vps, vms);

        // fold of all 12 RZ gates: phase by popcount (position-invariant)
#pragma unroll
        for (int k = 0; k < 16; ++k) {
            const int j = __popc(k);    // compile-time per unrolled k
            r[k] = __builtin_elementwise_fma((v2f){ r[k].y, r[k].y }, qp[j], qv[j] * r[k].x);
        }

        // ---- RT-2: CNOT gather back to canonical layout.
        // Write slots == the slots THIS thread read in RT-1 (bijective) -> no barrier.
#pragma unroll
        for (int k = 0; k < 16; ++k)
            psi[rb1 | ((k & 3) << 6) | ((k >> 2) << 10)] = r[k];
        __syncthreads();
#pragma unroll
        for (int k = 0; k < 16; ++k) {
            const int gk = (k ^ (k >> 1)) & 15;
            r[k] = psi[(gt ^ ((k & 1) << 7)) | (gk << 8)];
        }
    }
    __syncthreads();                    // all psi reads done before aliasing reuse

    // ---------------- measure <Z_w> from registers (canonical layout)
    float t_total = 0.f, s3 = 0.f, s2 = 0.f, s1 = 0.f, s0 = 0.f;
#pragma unroll
    for (int k = 0; k < 16; ++k) {
        const float pp = fmaf(r[k].x, r[k].x, r[k].y * r[k].y);
        t_total += pp;
        if (k & 1) s3 += pp;   // bit 8  -> wire 3
        if (k & 2) s2 += pp;   // bit 9  -> wire 2
        if (k & 4) s1 += pp;   // bit 10 -> wire 1
        if (k & 8) s0 += pp;   // bit 11 -> wire 0
    }
    float contrib[NW];
    contrib[3] = t_total - 2.f * s3;
    contrib[2] = t_total - 2.f * s2;
    contrib[1] = t_total - 2.f * s1;
    contrib[0] = t_total - 2.f * s0;
#pragma unroll
    for (int b = 0; b < 8; ++b) {
        const int w = 11 - b;                       // wires 11..4 from tid bits 0..7
        contrib[w] = ((tid >> b) & 1) ? -t_total : t_total;
    }
#pragma unroll
    for (int w = 0; w < NW; ++w) {
        float v = contrib[w];
        v += __shfl_down(v, 32);
        v += __shfl_down(v, 16);
        v += __shfl_down(v, 8);
        v += __shfl_down(v, 4);
        v += __shfl_down(v, 2);
        v += __shfl_down(v, 1);
        if (lane == 0) wred[wave * NW + w] = v;
    }
    __syncthreads();
    if (tid < NW)
        zfin[tid] = wred[tid] + wred[NW + tid] + wred[2 * NW + tid] + wred[3 * NW + tid];
    __syncthreads();

    // ---------------- head: out = z @ W2^T + b2
    if (tid < 10) {
        float o = b2[tid];
#pragma unroll
        for (int w = 0; w < NW; ++w)
            o = fmaf(zfin[w], W2[tid * NW + w], o);
        out[(size_t)blk * 10 + tid] = o;
    }
}

extern "C" void kernel_launch(void* const* d_in, const int* in_sizes, int n_in,
                              void* d_out, int out_size, void* d_ws, size_t ws_size,
                              hipStream_t stream) {
    const float* x   = (const float*)d_in[0];
    const float* W1  = (const float*)d_in[1];
    const float* b1  = (const float*)d_in[2];
    const float* ry  = (const float*)d_in[3];
    const float* rz  = (const float*)d_in[4];
    const float* W2  = (const float*)d_in[5];
    const float* b2  = (const float*)d_in[6];
    float* out = (float*)d_out;

    const int batch = in_sizes[0] / 784;   // 2048
    qmnist_kernel<<<batch, TPB, 0, stream>>>(x, W1, b1, ry, rz, W2, b2, out);
}

// Round 7
// 115.870 us; speedup vs baseline: 1.0843x; 1.0843x over previous
//
#include <hip/hip_runtime.h>
#include <math.h>

#define NW   12
#define DIM  4096
#define TPB  256

typedef float v2f __attribute__((ext_vector_type(2)));   // (re, im) -> v_pk_* f32

// DPP lane exchange (VALU, no LDS pipe).
// 0xB1=quad XOR1, 0x4E=quad XOR2, 0x1B=quad XOR3, 0x128=row_ror:8 (XOR8), 0x141=row_half_mirror (XOR7).
template<int CTRL>
__device__ __forceinline__ float fdpp(float v) {
    union { float f; int i; } u, w;
    u.f = v;
    w.i = __builtin_amdgcn_update_dpp(0, u.i, CTRL, 0xF, 0xF, false);
    return w.f;
}

// RY on register bit B (0..3 of the 16-amp register file). Packed-f32 VALU.
template<int B>
__device__ __forceinline__ void ry_reg(v2f* r, float c, v2f vps, v2f vms) {
#pragma unroll
    for (int p = 0; p < 8; ++p) {
        const int i0 = ((p >> B) << (B + 1)) | (p & ((1 << B) - 1));
        const int i1 = i0 | (1 << B);
        const v2f a = r[i0], b = r[i1];
        r[i0] = __builtin_elementwise_fma(vms, b, a * c);   // c*a - s*b
        r[i1] = __builtin_elementwise_fma(vps, a, b * c);   // s*a + c*b
    }
}

// RY via single-DPP partner exchange on a lane bit.
template<int CTRL>
__device__ __forceinline__ void ry_dpp(v2f* r, float c, v2f vsp) {
#pragma unroll
    for (int k = 0; k < 16; ++k) {
        const v2f p = { fdpp<CTRL>(r[k].x), fdpp<CTRL>(r[k].y) };
        r[k] = __builtin_elementwise_fma(vsp, p, r[k] * c);
    }
}

// RY on lane bit 2 (XOR4): partner = half_mirror(quad_xor3(x)) -> x[l^7^3] = x[l^4].
__device__ __forceinline__ void ry_xor4(v2f* r, float c, v2f vsp) {
#pragma unroll
    for (int k = 0; k < 16; ++k) {
        const v2f p = { fdpp<0x141>(fdpp<0x1B>(r[k].x)),
                        fdpp<0x141>(fdpp<0x1B>(r[k].y)) };
        r[k] = __builtin_elementwise_fma(vsp, p, r[k] * c);
    }
}

__global__ __launch_bounds__(TPB, 4)
void qmnist_kernel(const float* __restrict__ x,  const float* __restrict__ W1,
                   const float* __restrict__ b1, const float* __restrict__ ryp,
                   const float* __restrict__ rzp, const float* __restrict__ W2,
                   const float* __restrict__ b2, float* __restrict__ out) {
    // Exactly 32 KiB LDS. Small arrays alias the front (state lives in
    // registers whenever they are live; barriers order every transition).
    __shared__ v2f psi[DIM];
    float* smf  = (float*)psi;
    float* wred = smf;        // 48 floats
    float* encc = smf + 48;   // 12
    float* encs = smf + 60;   // 12
    float* zfin = smf + 72;   // 12

    const int tid  = threadIdx.x;
    const int blk  = blockIdx.x;
    const int lane = tid & 63;
    const int wave = tid >> 6;

    // ---------------- phase 0: feat = x[blk] @ W1^T + b1 -> encoding angles
    float acc[NW];
#pragma unroll
    for (int w = 0; w < NW; ++w) acc[w] = 0.f;
    if (tid < 196) {                      // 784 = 196 float4
        const float4 xv = ((const float4*)(x + (size_t)blk * 784))[tid];
#pragma unroll
        for (int w = 0; w < NW; ++w) {
            const float4 wv = ((const float4*)(W1 + w * 784))[tid];
            acc[w] = fmaf(xv.x, wv.x, fmaf(xv.y, wv.y, fmaf(xv.z, wv.z, xv.w * wv.w)));
        }
    }
#pragma unroll
    for (int w = 0; w < NW; ++w) {
        float v = acc[w];
        v += __shfl_down(v, 32);
        v += __shfl_down(v, 16);
        v += __shfl_down(v, 8);
        v += __shfl_down(v, 4);
        v += __shfl_down(v, 2);
        v += __shfl_down(v, 1);
        if (lane == 0) wred[wave * NW + w] = v;
    }
    __syncthreads();
    if (tid < NW) {
        float feat = wred[tid] + wred[NW + tid] + wred[2 * NW + tid] + wred[3 * NW + tid] + b1[tid];
        float a = tanhf(feat) * 3.14159265358979323846f;
        float h = 0.5f * a;
        encc[tid] = cosf(h);
        encs[tid] = sinf(h);
    }
    __syncthreads();

    // ---------------- init product state into REGISTERS.
    // amp index y = (k<<8)|tid; bit b of y <-> wire (11-b). bits 0..7 = tid, 8..11 = k.
    float hi = 1.f;
#pragma unroll
    for (int b = 0; b < 8; ++b)
        hi *= ((tid >> b) & 1) ? encs[11 - b] : encc[11 - b];
    v2f r[16];
#pragma unroll
    for (int k = 0; k < 16; ++k) {
        float f = hi;
        f *= (k & 1) ? encs[3] : encc[3];
        f *= (k & 2) ? encs[2] : encc[2];
        f *= (k & 4) ? encs[1] : encc[1];
        f *= (k & 8) ? encs[0] : encc[0];
        r[k] = (v2f){ f, 0.f };
    }

    // ---------------- variational params.
    // Layer = RY on all 12 positions, RZ on all 12 (folds to popcount phase,
    // layout-invariant), then CNOT staircase new[y] = old[y ^ (y>>1)].
    const float ry = ryp[0], rz = rzp[0];
    const float c = cosf(0.5f * ry), s = sinf(0.5f * ry);
    const v2f vps = {  s,  s };
    const v2f vms = { -s, -s };
    const int pcT = __popc(tid);
    v2f qv[5], qp[5];                    // cis(rz*(pcT+j-6)) and i*cis(...)
#pragma unroll
    for (int j = 0; j < 5; ++j) {
        const float ang = rz * (float)(pcT + j - 6);
        const float qc = cosf(ang), qs = sinf(ang);
        qv[j] = (v2f){  qc, qs };
        qp[j] = (v2f){ -qs, qc };
    }

    // per-lane signed s (splat) for the DPP RY gates (position = lane bit 0..3)
    const v2f vs0 = (lane & 1) ? vps : vms;   // position 0, XOR1  quad_perm
    const v2f vs1 = (lane & 2) ? vps : vms;   // position 1, XOR2  quad_perm
    const v2f vs2 = (lane & 4) ? vps : vms;   // position 2, XOR4  chained DPP
    const v2f vs3 = (lane & 8) ? vps : vms;   // position 3, XOR8  row_ror:8

    // RT addressing (identity slot map; every access = ONE base + imm, and
    // slot low4 = t0..t3 (rank-4) on all four patterns -> conflict-free b64):
    //  RT-1 write : psi[(k<<8)|tid]           low4 = t0..3
    //  RT-1 read  : base_r | (k<<4)           low4 = t0..3   (k' = positions 4-7)
    //  RT-2 write : same slots as RT-1 read (same thread -> no barrier)
    //  RT-2 read  : (gt ^ (k&1)<<7) | gray4(k)<<8   low4 = Gray(t0..3)
    const int base_r = (tid & 15) | ((tid & 240) << 4);  // t0-3 + t4..7 -> slots 8..11
    const int gt     = tid ^ (tid >> 1);                 // Gray of tid (bit7 = t7)

    for (int layer = 0; layer < 3; ++layer) {
        // ---- VALU gates, canonical layout: positions 8-11 (reg bits) ...
        ry_reg<0>(r, c, vps, vms); ry_reg<1>(r, c, vps, vms);
        ry_reg<2>(r, c, vps, vms); ry_reg<3>(r, c, vps, vms);
        // ... and positions 0-3 (lane bits 0-3) via DPP
        ry_dpp<0xB1>(r, c, vs0);
        ry_dpp<0x4E>(r, c, vs1);
        ry_xor4(r, c, vs2);
        ry_dpp<0x128>(r, c, vs3);

        // ---- RT-1: bring positions {4,5,6,7} into k'
        __syncthreads();                // prior psi readers done
#pragma unroll
        for (int k = 0; k < 16; ++k)
            psi[(k << 8) | tid] = r[k];
        __syncthreads();
#pragma unroll
        for (int k = 0; k < 16; ++k)
            r[k] = psi[base_r | (k << 4)];

        // gate positions 4,5,6,7 (now register bits 0-3)
        ry_reg<0>(r, c, vps, vms); ry_reg<1>(r, c, vps, vms);
        ry_reg<2>(r, c, vps, vms); ry_reg<3>(r, c, vps, vms);

        // fold of all 12 RZ gates: phase by popcount (position-invariant)
#pragma unroll
        for (int k = 0; k < 16; ++k) {
            const int j = __popc(k);    // compile-time per unrolled k
            r[k] = __builtin_elementwise_fma((v2f){ r[k].y, r[k].y }, qp[j], qv[j] * r[k].x);
        }

        // ---- RT-2: CNOT gather back to canonical layout.
        // Write slots == the slots THIS thread read in RT-1 (bijective) -> no
        // barrier; the storage map is the identity (slot == amp index).
#pragma unroll
        for (int k = 0; k < 16; ++k)
            psi[base_r | (k << 4)] = r[k];
        __syncthreads();
#pragma unroll
        for (int k = 0; k < 16; ++k) {
            const int gk = (k ^ (k >> 1)) & 15;
            r[k] = psi[(gt ^ ((k & 1) << 7)) | (gk << 8)];
        }
    }
    __syncthreads();                    // all psi reads done before aliasing reuse

    // ---------------- measure <Z_w> from registers (canonical layout)
    float t_total = 0.f, s3 = 0.f, s2 = 0.f, s1 = 0.f, s0 = 0.f;
#pragma unroll
    for (int k = 0; k < 16; ++k) {
        const float pp = fmaf(r[k].x, r[k].x, r[k].y * r[k].y);
        t_total += pp;
        if (k & 1) s3 += pp;   // bit 8  -> wire 3
        if (k & 2) s2 += pp;   // bit 9  -> wire 2
        if (k & 4) s1 += pp;   // bit 10 -> wire 1
        if (k & 8) s0 += pp;   // bit 11 -> wire 0
    }
    float contrib[NW];
    contrib[3] = t_total - 2.f * s3;
    contrib[2] = t_total - 2.f * s2;
    contrib[1] = t_total - 2.f * s1;
    contrib[0] = t_total - 2.f * s0;
#pragma unroll
    for (int b = 0; b < 8; ++b) {
        const int w = 11 - b;                       // wires 11..4 from tid bits 0..7
        contrib[w] = ((tid >> b) & 1) ? -t_total : t_total;
    }
#pragma unroll
    for (int w = 0; w < NW; ++w) {
        float v = contrib[w];
        v += __shfl_down(v, 32);
        v += __shfl_down(v, 16);
        v += __shfl_down(v, 8);
        v += __shfl_down(v, 4);
        v += __shfl_down(v, 2);
        v += __shfl_down(v, 1);
        if (lane == 0) wred[wave * NW + w] = v;
    }
    __syncthreads();
    if (tid < NW)
        zfin[tid] = wred[tid] + wred[NW + tid] + wred[2 * NW + tid] + wred[3 * NW + tid];
    __syncthreads();

    // ---------------- head: out = z @ W2^T + b2
    if (tid < 10) {
        float o = b2[tid];
#pragma unroll
        for (int w = 0; w < NW; ++w)
            o = fmaf(zfin[w], W2[tid * NW + w], o);
        out[(size_t)blk * 10 + tid] = o;
    }
}

extern "C" void kernel_launch(void* const* d_in, const int* in_sizes, int n_in,
                              void* d_out, int out_size, void* d_ws, size_t ws_size,
                              hipStream_t stream) {
    const float* x   = (const float*)d_in[0];
    const float* W1  = (const float*)d_in[1];
    const float* b1  = (const float*)d_in[2];
    const float* ry  = (const float*)d_in[3];
    const float* rz  = (const float*)d_in[4];
    const float* W2  = (const float*)d_in[5];
    const float* b2  = (const float*)d_in[6];
    float* out = (float*)d_out;

    const int batch = in_sizes[0] / 784;   // 2048
    qmnist_kernel<<<batch, TPB, 0, stream>>>(x, W1, b1, ry, rz, W2, b2, out);
}

// Round 8
// 115.609 us; speedup vs baseline: 1.0867x; 1.0022x over previous
//
#include <hip/hip_runtime.h>
#include <math.h>

#define NW   12
#define DIM  4096
#define TPB  256

typedef float v2f __attribute__((ext_vector_type(2)));   // (re, im) -> v_pk_* f32

// DPP lane exchange (VALU, no LDS pipe).
// 0xB1=quad XOR1, 0x4E=quad XOR2, 0x1B=quad XOR3, 0x128=row_ror:8 (XOR8), 0x141=row_half_mirror (XOR7).
template<int CTRL>
__device__ __forceinline__ float fdpp(float v) {
    union { float f; int i; } u, w;
    u.f = v;
    w.i = __builtin_amdgcn_update_dpp(0, u.i, CTRL, 0xF, 0xF, false);
    return w.f;
}

// RY on register bit B (0..3 of the 16-amp register file). Packed-f32 VALU.
template<int B>
__device__ __forceinline__ void ry_reg(v2f* r, float c, v2f vps, v2f vms) {
#pragma unroll
    for (int p = 0; p < 8; ++p) {
        const int i0 = ((p >> B) << (B + 1)) | (p & ((1 << B) - 1));
        const int i1 = i0 | (1 << B);
        const v2f a = r[i0], b = r[i1];
        r[i0] = __builtin_elementwise_fma(vms, b, a * c);   // c*a - s*b
        r[i1] = __builtin_elementwise_fma(vps, a, b * c);   // s*a + c*b
    }
}

// RY via single-DPP partner exchange on a lane bit.
template<int CTRL>
__device__ __forceinline__ void ry_dpp(v2f* r, float c, v2f vsp) {
#pragma unroll
    for (int k = 0; k < 16; ++k) {
        const v2f p = { fdpp<CTRL>(r[k].x), fdpp<CTRL>(r[k].y) };
        r[k] = __builtin_elementwise_fma(vsp, p, r[k] * c);
    }
}

// RY on lane bit 2 (XOR4): partner = half_mirror(quad_xor3(x)) -> x[l^7^3] = x[l^4].
__device__ __forceinline__ void ry_xor4(v2f* r, float c, v2f vsp) {
#pragma unroll
    for (int k = 0; k < 16; ++k) {
        const v2f p = { fdpp<0x141>(fdpp<0x1B>(r[k].x)),
                        fdpp<0x141>(fdpp<0x1B>(r[k].y)) };
        r[k] = __builtin_elementwise_fma(vsp, p, r[k] * c);
    }
}

__global__ __launch_bounds__(TPB, 4)
void qmnist_kernel(const float* __restrict__ x,  const float* __restrict__ W1,
                   const float* __restrict__ b1, const float* __restrict__ ryp,
                   const float* __restrict__ rzp, const float* __restrict__ W2,
                   const float* __restrict__ b2, float* __restrict__ out) {
    // Exactly 32 KiB LDS. Small arrays alias the front (state lives in
    // registers whenever they are live; barriers order every transition).
    __shared__ v2f psi[DIM];
    float* smf  = (float*)psi;
    float* wred = smf;        // 48 floats
    float* encc = smf + 48;   // 12
    float* encs = smf + 60;   // 12
    float* zfin = smf + 72;   // 12

    const int tid  = threadIdx.x;
    const int blk  = blockIdx.x;
    const int lane = tid & 63;
    const int wave = tid >> 6;

    // ---------------- phase 0: feat = x[blk] @ W1^T + b1 -> encoding angles
    float acc[NW];
#pragma unroll
    for (int w = 0; w < NW; ++w) acc[w] = 0.f;
    if (tid < 196) {                      // 784 = 196 float4
        const float4 xv = ((const float4*)(x + (size_t)blk * 784))[tid];
#pragma unroll
        for (int w = 0; w < NW; ++w) {
            const float4 wv = ((const float4*)(W1 + w * 784))[tid];
            acc[w] = fmaf(xv.x, wv.x, fmaf(xv.y, wv.y, fmaf(xv.z, wv.z, xv.w * wv.w)));
        }
    }
#pragma unroll
    for (int w = 0; w < NW; ++w) {
        float v = acc[w];
        v += __shfl_down(v, 32);
        v += __shfl_down(v, 16);
        v += __shfl_down(v, 8);
        v += __shfl_down(v, 4);
        v += __shfl_down(v, 2);
        v += __shfl_down(v, 1);
        if (lane == 0) wred[wave * NW + w] = v;
    }
    __syncthreads();
    if (tid < NW) {
        float feat = wred[tid] + wred[NW + tid] + wred[2 * NW + tid] + wred[3 * NW + tid] + b1[tid];
        float a = tanhf(feat) * 3.14159265358979323846f;
        float h = 0.5f * a;
        encc[tid] = cosf(h);
        encs[tid] = sinf(h);
    }
    __syncthreads();

    // ---------------- init product state into REGISTERS.
    // amp index y = (k<<8)|tid; bit b of y <-> wire (11-b). bits 0..7 = tid, 8..11 = k.
    float hi = 1.f;
#pragma unroll
    for (int b = 0; b < 8; ++b)
        hi *= ((tid >> b) & 1) ? encs[11 - b] : encc[11 - b];
    v2f r[16];
#pragma unroll
    for (int k = 0; k < 16; ++k) {
        float f = hi;
        f *= (k & 1) ? encs[3] : encc[3];
        f *= (k & 2) ? encs[2] : encc[2];
        f *= (k & 4) ? encs[1] : encc[1];
        f *= (k & 8) ? encs[0] : encc[0];
        r[k] = (v2f){ f, 0.f };
    }

    // ---------------- variational params.
    // Layer = RY on all 12 positions, RZ on all 12 (folds to popcount phase,
    // layout-invariant), then CNOT staircase new[y] = old[y ^ (y>>1)].
    // Layer 3: RZ is a pure phase (|amp|^2 invariant) -> skipped; CNOT is
    // folded into the measurement signs (see measure phase).
    const float ry = ryp[0], rz = rzp[0];
    const float c = cosf(0.5f * ry), s = sinf(0.5f * ry);
    const v2f vps = {  s,  s };
    const v2f vms = { -s, -s };
    const int pcT = __popc(tid);
    v2f qv[5], qp[5];                    // cis(rz*(pcT+j-6)) and i*cis(...)
#pragma unroll
    for (int j = 0; j < 5; ++j) {
        const float ang = rz * (float)(pcT + j - 6);
        const float qc = cosf(ang), qs = sinf(ang);
        qv[j] = (v2f){  qc, qs };
        qp[j] = (v2f){ -qs, qc };
    }

    // per-lane signed s (splat) for the DPP RY gates (position = lane bit 0..3)
    const v2f vs0 = (lane & 1) ? vps : vms;   // position 0, XOR1  quad_perm
    const v2f vs1 = (lane & 2) ? vps : vms;   // position 1, XOR2  quad_perm
    const v2f vs2 = (lane & 4) ? vps : vms;   // position 2, XOR4  chained DPP
    const v2f vs3 = (lane & 8) ? vps : vms;   // position 3, XOR8  row_ror:8

    // RT addressing (identity slot map; every access = ONE base + imm, and
    // slot low4 = t0..t3 (rank-4) on all four patterns -> conflict-free b64):
    //  RT-1 write : psi[(k<<8)|tid]           low4 = t0..3
    //  RT-1 read  : base_r | (k<<4)           low4 = t0..3   (k' = positions 4-7)
    //  RT-2 write : same slots as RT-1 read (same thread -> no barrier)
    //  RT-2 read  : (gt ^ (k&1)<<7) | gray4(k)<<8   low4 = Gray(t0..3)
    const int base_r = (tid & 15) | ((tid & 240) << 4);  // t0-3 + t4..7 -> slots 8..11
    const int gt     = tid ^ (tid >> 1);                 // Gray of tid (bit7 = t7)

    // ---------------- layers 0,1 (full: gates + RZ + CNOT gather)
    for (int layer = 0; layer < 2; ++layer) {
        __syncthreads();                // prior psi readers done

        // RY on positions 8-11 (reg bits), canonical layout
        ry_reg<0>(r, c, vps, vms); ry_reg<1>(r, c, vps, vms);
        ry_reg<2>(r, c, vps, vms); ry_reg<3>(r, c, vps, vms);

        // ---- RT-1: bring positions {4,5,6,7} into k'
#pragma unroll
        for (int k = 0; k < 16; ++k)
            psi[(k << 8) | tid] = r[k];
        __syncthreads();
#pragma unroll
        for (int k = 0; k < 16; ++k)
            r[k] = psi[base_r | (k << 4)];

        // positions 0-3 stay at lane bits through the swap: DPP gates here,
        // per-k independent -> overlaps the LDS read latency.
        ry_dpp<0xB1>(r, c, vs0);
        ry_dpp<0x4E>(r, c, vs1);
        ry_xor4(r, c, vs2);
        ry_dpp<0x128>(r, c, vs3);

        // gate positions 4,5,6,7 (now register bits 0-3)
        ry_reg<0>(r, c, vps, vms); ry_reg<1>(r, c, vps, vms);
        ry_reg<2>(r, c, vps, vms); ry_reg<3>(r, c, vps, vms);

        // fold of all 12 RZ gates: phase by popcount (position-invariant)
#pragma unroll
        for (int k = 0; k < 16; ++k) {
            const int j = __popc(k);    // compile-time per unrolled k
            r[k] = __builtin_elementwise_fma((v2f){ r[k].y, r[k].y }, qp[j], qv[j] * r[k].x);
        }

        // ---- RT-2: CNOT gather back to canonical layout.
        // Write slots == the slots THIS thread read in RT-1 (bijective) -> no
        // barrier; the storage map is the identity (slot == amp index).
#pragma unroll
        for (int k = 0; k < 16; ++k)
            psi[base_r | (k << 4)] = r[k];
        __syncthreads();
#pragma unroll
        for (int k = 0; k < 16; ++k) {
            const int gk = (k ^ (k >> 1)) & 15;
            r[k] = psi[(gt ^ ((k & 1) << 7)) | (gk << 8)];
        }
    }

    // ---------------- layer 2: gates only; RZ + CNOT folded into measurement
    __syncthreads();
    ry_reg<0>(r, c, vps, vms); ry_reg<1>(r, c, vps, vms);
    ry_reg<2>(r, c, vps, vms); ry_reg<3>(r, c, vps, vms);
#pragma unroll
    for (int k = 0; k < 16; ++k)
        psi[(k << 8) | tid] = r[k];
    __syncthreads();
#pragma unroll
    for (int k = 0; k < 16; ++k)
        r[k] = psi[base_r | (k << 4)];
    ry_dpp<0xB1>(r, c, vs0);
    ry_dpp<0x4E>(r, c, vs1);
    ry_xor4(r, c, vs2);
    ry_dpp<0x128>(r, c, vs3);
    ry_reg<0>(r, c, vps, vms); ry_reg<1>(r, c, vps, vms);
    ry_reg<2>(r, c, vps, vms); ry_reg<3>(r, c, vps, vms);
    __syncthreads();                    // all psi reads done before aliasing reuse

    // ---------------- measure <Z_w> with CNOT folded into signs.
    // State held: amp u = t0-3 | k<<4 | t4-7<<8 (pre-CNOT, phase-free modulus).
    // psi_post[v] = phi[v ^ (v>>1)]  =>  v_b = parity(u >> b), so
    // <Z_w> = sum_u (-1)^{parity(u >> (11-w))} |phi[u]|^2.
    float T = 0.f, Sp = 0.f, S1 = 0.f, S2 = 0.f, S3 = 0.f;
#pragma unroll
    for (int k = 0; k < 16; ++k) {
        const float pp = fmaf(r[k].x, r[k].x, r[k].y * r[k].y);
        T += pp;
        Sp += (__popc(k) & 1)        ? -pp : pp;   // parity(k)
        S1 += (__popc(k >> 1) & 1)   ? -pp : pp;   // parity(k>>1)
        S2 += (__popc(k >> 2) & 1)   ? -pp : pp;   // parity(k>>2)
        S3 += ((k >> 3) & 1)         ? -pp : pp;   // parity(k>>3)
    }
    const int t1 = (tid >> 1) & 1, t2 = (tid >> 2) & 1, t3 = (tid >> 3) & 1;
    const int t4 = (tid >> 4) & 1, t5 = (tid >> 5) & 1, t6 = (tid >> 6) & 1,
              t7 = (tid >> 7) & 1;
    const int p47 = t4 ^ t5 ^ t6 ^ t7;
    float contrib[NW];
    contrib[0]  = t7                  ? -T : T;    // b=11
    contrib[1]  = (t6 ^ t7)           ? -T : T;    // b=10
    contrib[2]  = (t5 ^ t6 ^ t7)      ? -T : T;    // b=9
    contrib[3]  = p47                 ? -T : T;    // b=8
    contrib[4]  = p47                 ? -S3 : S3;  // b=7
    contrib[5]  = p47                 ? -S2 : S2;  // b=6
    contrib[6]  = p47                 ? -S1 : S1;  // b=5
    contrib[7]  = p47                 ? -Sp : Sp;  // b=4
    contrib[8]  = (t3 ^ p47)          ? -Sp : Sp;  // b=3
    contrib[9]  = (t2 ^ t3 ^ p47)     ? -Sp : Sp;  // b=2
    contrib[10] = (t1 ^ t2 ^ t3 ^ p47) ? -Sp : Sp; // b=1
    contrib[11] = (pcT & 1)           ? -Sp : Sp;  // b=0: parity(tid)
#pragma unroll
    for (int w = 0; w < NW; ++w) {
        float v = contrib[w];
        v += __shfl_down(v, 32);
        v += __shfl_down(v, 16);
        v += __shfl_down(v, 8);
        v += __shfl_down(v, 4);
        v += __shfl_down(v, 2);
        v += __shfl_down(v, 1);
        if (lane == 0) wred[wave * NW + w] = v;
    }
    __syncthreads();
    if (tid < NW)
        zfin[tid] = wred[tid] + wred[NW + tid] + wred[2 * NW + tid] + wred[3 * NW + tid];
    __syncthreads();

    // ---------------- head: out = z @ W2^T + b2
    if (tid < 10) {
        float o = b2[tid];
#pragma unroll
        for (int w = 0; w < NW; ++w)
            o = fmaf(zfin[w], W2[tid * NW + w], o);
        out[(size_t)blk * 10 + tid] = o;
    }
}

extern "C" void kernel_launch(void* const* d_in, const int* in_sizes, int n_in,
                              void* d_out, int out_size, void* d_ws, size_t ws_size,
                              hipStream_t stream) {
    const float* x   = (const float*)d_in[0];
    const float* W1  = (const float*)d_in[1];
    const float* b1  = (const float*)d_in[2];
    const float* ry  = (const float*)d_in[3];
    const float* rz  = (const float*)d_in[4];
    const float* W2  = (const float*)d_in[5];
    const float* b2  = (const float*)d_in[6];
    float* out = (float*)d_out;

    const int batch = in_sizes[0] / 784;   // 2048
    qmnist_kernel<<<batch, TPB, 0, stream>>>(x, W1, b1, ry, rz, W2, b2, out);
}